// Round 22
// baseline (233.619 us; speedup 1.0000x reference)
//
#include <hip/hip_runtime.h>
#include <hip/hip_bf16.h>

// Problem constants (reference: B=2, T=2048, C=2048, NH=16, NKV=4, HD=128, GATE_CH=12)
#define BB   2
#define TT   2048
#define CC   2048
#define NHq  16
#define NKVq 4
#define HDq  128
#define ROWS (BB*TT)          // 4096
#define NQKV (NHq*HDq + 2*NKVq*HDq)  // 3072

using bf16 = __hip_bfloat16;
using short8  = __attribute__((ext_vector_type(8))) short;
using short4v = __attribute__((ext_vector_type(4))) short;
using f32x4   = __attribute__((ext_vector_type(4))) float;

#define MFMA16(a,b,c) __builtin_amdgcn_mfma_f32_16x16x32_bf16((a),(b),(c),0,0,0)

// async global->LDS, 16B per lane. LDS dest must be wave-uniform-base + lane*16.
__device__ __forceinline__ void gll16(const bf16* g, void* l) {
    __builtin_amdgcn_global_load_lds((const __attribute__((address_space(1))) void*)g,
                                     (__attribute__((address_space(3))) void*)l,
                                     16, 0, 0);
}

// ---------------- fused cast: all fp32 inputs -> contiguous bf16 ws regions ----------------
__global__ void cast_all(const float* __restrict__ x,  const float* __restrict__ wq,
                         const float* __restrict__ wk, const float* __restrict__ wv,
                         const float* __restrict__ wp, bf16* __restrict__ dst) {
    long e = ((long)blockIdx.x * 256 + threadIdx.x) * 4;
    const float* src; long off;
    if (e < 8388608L)       { src = x;  off = e; }
    else if (e < 12582912L) { src = wq; off = e - 8388608L; }
    else if (e < 13631488L) { src = wk; off = e - 12582912L; }
    else if (e < 14680064L) { src = wv; off = e - 13631488L; }
    else                    { src = wp; off = e - 14680064L; }
    float4 v = *reinterpret_cast<const float4*>(src + off);
    ushort4 o;
    o.x = __bfloat16_as_ushort(__float2bfloat16(v.x));
    o.y = __bfloat16_as_ushort(__float2bfloat16(v.y));
    o.z = __bfloat16_as_ushort(__float2bfloat16(v.z));
    o.w = __bfloat16_as_ushort(__float2bfloat16(v.w));
    *reinterpret_cast<ushort4*>(dst + e) = o;
}

// ---------------- bf16 MFMA GEMM: 128x128 tile, BK=64, XOR-swizzled LDS (R12 best) ----------------
template<int OUT_F32>
__global__ __launch_bounds__(256) void gemm_bt(const bf16* __restrict__ A,
                                               const bf16* __restrict__ B,
                                               void* __restrict__ Cp,
                                               int M, int N, int K) {
    const int bm = blockIdx.x * 128;
    const int bn = blockIdx.y * 128;
    const int tid = threadIdx.x;
    const int lane = tid & 63;
    const int w = tid >> 6;
    const int wr = w >> 1, wc = w & 1;   // 2x2 waves of 64x64

    __shared__ __align__(16) bf16 As[128 * 64];   // 16 KB, swizzled storage
    __shared__ __align__(16) bf16 Bs[128 * 64];   // 16 KB

    f32x4 acc[4][4];
#pragma unroll
    for (int i = 0; i < 4; ++i)
#pragma unroll
        for (int j = 0; j < 4; ++j) acc[i][j] = f32x4{0.f, 0.f, 0.f, 0.f};

    const int srow = tid >> 3;          // 0..31 (+ i*32)
    const int sch  = tid & 7;           // dest 16B chunk

    const int fr = lane & 15;
    const int kq = lane >> 4;           // 0..3

    for (int k0 = 0; k0 < K; k0 += 64) {
        __syncthreads();
#pragma unroll
        for (int i = 0; i < 4; ++i) {
            int row = i * 32 + srow;
            int c = sch ^ (row & 7);    // pre-swizzled source chunk
            gll16(&A[(size_t)(bm + row) * K + k0 + c * 8], (char*)As + i * 4096 + tid * 16);
            gll16(&B[(size_t)(bn + row) * K + k0 + c * 8], (char*)Bs + i * 4096 + tid * 16);
        }
        __syncthreads();

#pragma unroll
        for (int kk = 0; kk < 2; ++kk) {
            short8 af[4], bfr[4];
#pragma unroll
            for (int m = 0; m < 4; ++m) {
                int r = wr * 64 + m * 16 + fr;
                af[m] = *reinterpret_cast<const short8*>(
                    (const char*)As + r * 128 + (((kk * 4 + kq) ^ (r & 7)) * 16));
            }
#pragma unroll
            for (int n = 0; n < 4; ++n) {
                int r = wc * 64 + n * 16 + fr;
                bfr[n] = *reinterpret_cast<const short8*>(
                    (const char*)Bs + r * 128 + (((kk * 4 + kq) ^ (r & 7)) * 16));
            }
            __builtin_amdgcn_s_setprio(1);
#pragma unroll
            for (int m = 0; m < 4; ++m)
#pragma unroll
                for (int n = 0; n < 4; ++n)
                    acc[m][n] = MFMA16(af[m], bfr[n], acc[m][n]);
            __builtin_amdgcn_s_setprio(0);
        }
    }

    const int cr = (lane >> 4) * 4;
    const int cc = lane & 15;
#pragma unroll
    for (int m = 0; m < 4; ++m)
#pragma unroll
        for (int n = 0; n < 4; ++n) {
            int row = bm + wr * 64 + m * 16 + cr;
            int col = bn + wc * 64 + n * 16 + cc;
#pragma unroll
            for (int j = 0; j < 4; ++j) {
                float v = acc[m][n][j];
                if (OUT_F32) ((float*)Cp)[(size_t)(row + j) * N + col] = v;
                else         ((bf16*)Cp)[(size_t)(row + j) * N + col] = __float2bfloat16(v);
            }
        }
}

// ---------------- postproc v2 (vectorized) ----------------
__global__ __launch_bounds__(256) void postproc(const float* __restrict__ x,
                                                const float* __restrict__ ve,
                                                const float* __restrict__ cosb,
                                                const float* __restrict__ sinb,
                                                const float* __restrict__ Wgate,
                                                bf16* __restrict__ qkv) {
    const int row = blockIdx.x;            // b*T + t
    const int t = row & (TT - 1);
    const int tid = threadIdx.x;
    __shared__ float gate_s[NKVq];
    if (tid < NKVq) {
        float g = 0.f;
#pragma unroll
        for (int c = 0; c < 12; ++c) g += x[(size_t)row * CC + c] * Wgate[tid * 12 + c];
        gate_s[tid] = 3.0f / (1.0f + __expf(-g));
    }
    __syncthreads();

    bf16* qkvr = qkv + (size_t)row * NQKV;

    if (tid < 160) {
        const int hh = tid >> 3, c = tid & 7;
        const int off = (hh < NHq) ? hh * HDq : 2048 + (hh - NHq) * HDq;
        const int d0 = c * 8;
        short8 x1v = *reinterpret_cast<const short8*>(&qkvr[off + d0]);
        short8 x2v = *reinterpret_cast<const short8*>(&qkvr[off + 64 + d0]);
        float4 c0 = *reinterpret_cast<const float4*>(&cosb[(size_t)t * 64 + d0]);
        float4 c1 = *reinterpret_cast<const float4*>(&cosb[(size_t)t * 64 + d0 + 4]);
        float4 s0 = *reinterpret_cast<const float4*>(&sinb[(size_t)t * 64 + d0]);
        float4 s1 = *reinterpret_cast<const float4*>(&sinb[(size_t)t * 64 + d0 + 4]);
        float cv[8] = {c0.x, c0.y, c0.z, c0.w, c1.x, c1.y, c1.z, c1.w};
        float sv[8] = {s0.x, s0.y, s0.z, s0.w, s1.x, s1.y, s1.z, s1.w};
        float r1[8], r2[8], ss = 0.f;
#pragma unroll
        for (int e = 0; e < 8; ++e) {
            float x1 = __bfloat162float(__ushort_as_bfloat16((ushort)x1v[e]));
            float x2 = __bfloat162float(__ushort_as_bfloat16((ushort)x2v[e]));
            r1[e] =  x1 * cv[e] + x2 * sv[e];
            r2[e] = -x1 * sv[e] + x2 * cv[e];
            ss += r1[e] * r1[e] + r2[e] * r2[e];
        }
#pragma unroll
        for (int m = 1; m < 8; m <<= 1) ss += __shfl_xor(ss, m);
        float sc = rsqrtf(ss * (1.0f / 128.0f) + 1e-6f) * 1.2f;
        short8 o1, o2;
#pragma unroll
        for (int e = 0; e < 8; ++e) {
            o1[e] = (short)__bfloat16_as_ushort(__float2bfloat16(r1[e] * sc));
            o2[e] = (short)__bfloat16_as_ushort(__float2bfloat16(r2[e] * sc));
        }
        *reinterpret_cast<short8*>(&qkvr[off + d0])      = o1;
        *reinterpret_cast<short8*>(&qkvr[off + 64 + d0]) = o2;
    } else if (tid < 224) {
        const int u = tid - 160;
        const int e0 = u * 8;
        short8 vv = *reinterpret_cast<const short8*>(&qkvr[2560 + e0]);
        float4 v0 = *reinterpret_cast<const float4*>(&ve[(size_t)row * 512 + e0]);
        float4 v1 = *reinterpret_cast<const float4*>(&ve[(size_t)row * 512 + e0 + 4]);
        float vef[8] = {v0.x, v0.y, v0.z, v0.w, v1.x, v1.y, v1.z, v1.w};
        const float g = gate_s[u >> 4];
        short8 o;
#pragma unroll
        for (int e = 0; e < 8; ++e) {
            float v = __bfloat162float(__ushort_as_bfloat16((ushort)vv[e])) + g * vef[e];
            o[e] = (short)__bfloat16_as_ushort(__float2bfloat16(v));
        }
        *reinterpret_cast<short8*>(&qkvr[2560 + e0]) = o;
    }
}

// ---------------- attn v11: split-KV (2 parts), 48 KB LDS -> 3 blocks/CU ----------------
// Fixed-cap softmax makes partials associative: each part writes unnormalized
// Osum (bf16) + l (f32); combine kernel divides. Single-buffer K staged between
// barriers (v8-proven); V reg-prefetch; prescaled Q.
__global__ __launch_bounds__(256) void attn_split(const bf16* __restrict__ qkv,
                                                  bf16* __restrict__ O0,
                                                  bf16* __restrict__ O1,
                                                  float* __restrict__ lbuf,
                                                  const int* __restrict__ winp) {
    const int bid = blockIdx.x;
    const int part = bid >> 9;           // 0 = diagonal half, 1 = older half
    const int inner = bid & 511;
    const int group = inner >> 8, idx = inner & 255;
    const int bh = idx >> 3, jj = idx & 7;
    const int qt = group ? jj : (15 - jj);
    const int h = bh & 15, b = bh >> 4;
    const int t0 = qt * 128;
    const int kvh = h >> 2;
    const int tid = threadIdx.x;
    const int lane = tid & 63;
    const int w = tid >> 6;
    const int window = winp[0];

    __shared__ __align__(16) bf16 Ks[64 * 128];     // 16 KB
    __shared__ __align__(16) bf16 Vt[128 * 64];     // 16 KB
    __shared__ __align__(16) bf16 Ps[4][32 * 64];   // 16 KB

    const int fr = lane & 15;
    const int kq = (lane >> 4) * 8;
    const int hi = lane >> 4;
    const float scl2 = 0.08838834764831845f * 1.4426950408889634f;
    const float CAP = 24.0f;

    short8 qf[2][4];
#pragma unroll
    for (int mi = 0; mi < 2; ++mi) {
        const bf16* qp = qkv + ((size_t)(b * TT) + t0 + w * 32 + mi * 16 + fr) * NQKV + h * HDq;
#pragma unroll
        for (int c = 0; c < 4; ++c) {
            short8 v = *reinterpret_cast<const short8*>(&qp[c * 32 + kq]);
#pragma unroll
            for (int e = 0; e < 8; ++e) {
                float f = __bfloat162float(__ushort_as_bfloat16((ushort)v[e])) * scl2;
                v[e] = (short)__bfloat16_as_ushort(__float2bfloat16(f));
            }
            qf[mi][c] = v;
        }
    }

    f32x4 acc[2][8];
#pragma unroll
    for (int mi = 0; mi < 2; ++mi)
#pragma unroll
        for (int n = 0; n < 8; ++n) acc[mi][n] = f32x4{0.f, 0.f, 0.f, 0.f};
    float lrow[2][4];
#pragma unroll
    for (int mi = 0; mi < 2; ++mi)
#pragma unroll
        for (int j = 0; j < 4; ++j) lrow[mi][j] = 0.f;

    int s_lo = t0 - window; if (s_lo < 0) s_lo = 0; s_lo &= ~63;
    const int NT = ((t0 + 128) - s_lo) >> 6;     // even (window % 64 == 0)
    const int halfn = NT >> 1;
    const int sk0 = part ? s_lo : s_lo + halfn * 64;
    const int skE = part ? s_lo + halfn * 64 : t0 + 128;

    const bf16* Kg = qkv + (size_t)b * TT * NQKV + 2048 + kvh * HDq;
    const bf16* Vg = Kg + 512;

    const int str = tid >> 4;
    const int sti = tid & 15;
    const int vf  = tid & 15;
    const int vdc = (tid >> 4) * 8;

    short8 vr[4];

    // ---- prime: stage tile sk0 ----
#pragma unroll
    for (int p = 0; p < 4; ++p) {
        int row = p * 16 + str;
        int c16 = sti ^ (row & 7);
        gll16(&Kg[(size_t)(sk0 + row) * NQKV + c16 * 8], (char*)Ks + p * 4096 + tid * 16);
    }
#pragma unroll
    for (int i = 0; i < 4; ++i)
        vr[i] = *reinterpret_cast<const short8*>(&Vg[(size_t)(sk0 + 16 * i + vf) * NQKV + vdc]);
#pragma unroll
    for (int j = 0; j < 8; ++j) {
        short4v col;
        col[0] = vr[0][j]; col[1] = vr[1][j]; col[2] = vr[2][j]; col[3] = vr[3][j];
        *reinterpret_cast<short4v*>((char*)Vt + (vdc + j) * 128 + ((8 * vf) ^ (j << 4))) = col;
    }
    __syncthreads();

    for (int sk = sk0; sk < skE; sk += 64) {
        const bool hn = (sk + 64 < skE);

        if (hn) {
#pragma unroll
            for (int i = 0; i < 4; ++i)
                vr[i] = *reinterpret_cast<const short8*>(&Vg[(size_t)(sk + 64 + 16 * i + vf) * NQKV + vdc]);
        }

        // ---- QK^T ----
        f32x4 S[2][4];
#pragma unroll
        for (int mi = 0; mi < 2; ++mi)
#pragma unroll
            for (int n = 0; n < 4; ++n) S[mi][n] = f32x4{0.f, 0.f, 0.f, 0.f};
        __builtin_amdgcn_s_setprio(1);
#pragma unroll
        for (int n = 0; n < 4; ++n) {
            int rb = n * 16 + fr;
#pragma unroll
            for (int c = 0; c < 4; ++c) {
                int colb = c * 64 + kq * 2;
                short8 kf = *reinterpret_cast<const short8*>(
                    (const char*)Ks + rb * 256 + (colb ^ ((rb & 7) << 4)));
                S[0][n] = MFMA16(qf[0][c], kf, S[0][n]);
                S[1][n] = MFMA16(qf[1][c], kf, S[1][n]);
            }
        }
        __builtin_amdgcn_s_setprio(0);

        // ---- fixed-cap softmax -> Ps ----
        const int rw0 = t0 + w * 32;
        const bool interior = (sk + 63 <= rw0) && (rw0 + 31 - sk <= window);
#pragma unroll
        for (int mi = 0; mi < 2; ++mi) {
#pragma unroll
            for (int j = 0; j < 4; ++j) {
                const int rl = hi * 4 + j;
                float s0, s1, s2, s3;
                if (interior) {
                    s0 = S[mi][0][j]; s1 = S[mi][1][j];
                    s2 = S[mi][2][j]; s3 = S[mi][3][j];
                } else {
                    const int r = rw0 + mi * 16 + rl;
                    int c0 = sk + fr, c1 = c0 + 16, c2 = c0 + 32, c3 = c0 + 48;
                    s0 = (c0 <= r && r - c0 <= window) ? S[mi][0][j] : -1e30f;
                    s1 = (c1 <= r && r - c1 <= window) ? S[mi][1][j] : -1e30f;
                    s2 = (c2 <= r && r - c2 <= window) ? S[mi][2][j] : -1e30f;
                    s3 = (c3 <= r && r - c3 <= window) ? S[mi][3][j] : -1e30f;
                }
                float p0 = exp2f(s0 - CAP);
                float p1 = exp2f(s1 - CAP);
                float p2 = exp2f(s2 - CAP);
                float p3 = exp2f(s3 - CAP);
                lrow[mi][j] += (p0 + p1) + (p2 + p3);
                short4v pk;
                pk[0] = (short)__bfloat16_as_ushort(__float2bfloat16(p0));
                pk[1] = (short)__bfloat16_as_ushort(__float2bfloat16(p1));
                pk[2] = (short)__bfloat16_as_ushort(__float2bfloat16(p2));
                pk[3] = (short)__bfloat16_as_ushort(__float2bfloat16(p3));
                const int prow = mi * 16 + rl;
                *reinterpret_cast<short4v*>(
                    (char*)Ps + w * 4096 + prow * 128 + ((8 * fr) ^ ((prow & 7) << 4))) = pk;
            }
        }

        __syncthreads();   // barrier A: Ks consumed

        if (hn) {
#pragma unroll
            for (int p = 0; p < 4; ++p) {
                int row = p * 16 + str;
                int c16 = sti ^ (row & 7);
                gll16(&Kg[(size_t)(sk + 64 + row) * NQKV + c16 * 8], (char*)Ks + p * 4096 + tid * 16);
            }
        }

        // ---- PV ----
        __builtin_amdgcn_s_setprio(1);
#pragma unroll
        for (int c2 = 0; c2 < 2; ++c2) {
            short8 pa0 = *reinterpret_cast<const short8*>(
                (char*)Ps + w * 4096 + fr * 128 + ((c2 * 64 + hi * 16) ^ ((fr & 7) << 4)));
            short8 pa1 = *reinterpret_cast<const short8*>(
                (char*)Ps + w * 4096 + (16 + fr) * 128 + ((c2 * 64 + hi * 16) ^ ((fr & 7) << 4)));
#pragma unroll
            for (int n = 0; n < 8; ++n) {
                short8 vb = *reinterpret_cast<const short8*>(
                    (char*)Vt + (n * 16 + fr) * 128 + ((c2 * 64 + hi * 16) ^ ((fr & 7) << 4)));
                acc[0][n] = MFMA16(pa0, vb, acc[0][n]);
                acc[1][n] = MFMA16(pa1, vb, acc[1][n]);
            }
        }
        __builtin_amdgcn_s_setprio(0);

        __syncthreads();   // barrier B: Vt consumed; K gll16 drained

        if (hn) {
#pragma unroll
            for (int j = 0; j < 8; ++j) {
                short4v col;
                col[0] = vr[0][j]; col[1] = vr[1][j]; col[2] = vr[2][j]; col[3] = vr[3][j];
                *reinterpret_cast<short4v*>((char*)Vt + (vdc + j) * 128 + ((8 * vf) ^ (j << 4))) = col;
            }
        }
    }

    // ---- epilogue: write UNNORMALIZED Osum (bf16) + l (f32) ----
    bf16* ob = part ? O1 : O0;
    float* lb = lbuf + (size_t)part * ROWS * NHq;
#pragma unroll
    for (int mi = 0; mi < 2; ++mi)
#pragma unroll
        for (int j = 0; j < 4; ++j) {
            float l = lrow[mi][j];
#pragma unroll
            for (int mm = 1; mm < 16; mm <<= 1) l += __shfl_xor(l, mm);
            const int r = t0 + w * 32 + mi * 16 + hi * 4 + j;
            bf16* yr = ob + ((size_t)(b * TT) + r) * CC + h * HDq;
#pragma unroll
            for (int n = 0; n < 8; ++n)
                yr[n * 16 + fr] = __float2bfloat16(acc[mi][n][j]);
            if (fr == 0) lb[((size_t)(b * TT) + r) * NHq + h] = l;
        }
}

// ---------------- combine: y = (O0 + O1) / (l0 + l1), in place into O0 ----------------
__global__ __launch_bounds__(256) void attn_combine(bf16* __restrict__ O0,
                                                    const bf16* __restrict__ O1,
                                                    const float* __restrict__ lbuf) {
    const int row = blockIdx.x;
    const int tid = threadIdx.x;
    const int h = tid >> 4;
    const size_t off = (size_t)row * CC + tid * 8;
    float l = lbuf[(size_t)row * NHq + h] + lbuf[(size_t)ROWS * NHq + (size_t)row * NHq + h];
    float inv = 1.f / l;
    short8 a = *reinterpret_cast<const short8*>(O0 + off);
    short8 c = *reinterpret_cast<const short8*>(O1 + off);
    short8 o;
#pragma unroll
    for (int e = 0; e < 8; ++e) {
        float fa = __bfloat162float(__ushort_as_bfloat16((ushort)a[e]));
        float fc = __bfloat162float(__ushort_as_bfloat16((ushort)c[e]));
        o[e] = (short)__bfloat16_as_ushort(__float2bfloat16((fa + fc) * inv));
    }
    *reinterpret_cast<short8*>(O0 + off) = o;
}

// ---------------- attn v9 fallback (unsplit; used if ws too small) ----------------
__global__ __launch_bounds__(256, 2) void attn_mfma(const bf16* __restrict__ qkv,
                                                    bf16* __restrict__ y,
                                                    const int* __restrict__ winp) {
    const int bid = blockIdx.x;
    const int group = bid >> 8, idx = bid & 255;
    const int bh = idx >> 3, jj = idx & 7;
    const int qt = group ? jj : (15 - jj);
    const int h = bh & 15, b = bh >> 4;
    const int t0 = qt * 128;
    const int kvh = h >> 2;
    const int tid = threadIdx.x;
    const int lane = tid & 63;
    const int w = tid >> 6;
    const int window = winp[0];

    __shared__ __align__(16) bf16 Ks[2][64 * 128];
    __shared__ __align__(16) bf16 Vt[2][128 * 64];
    __shared__ __align__(16) bf16 Ps[4][32 * 64];

    const int fr = lane & 15;
    const int kq = (lane >> 4) * 8;
    const int hi = lane >> 4;
    const float scl2 = 0.08838834764831845f * 1.4426950408889634f;
    const float CAP = 24.0f;

    short8 qf[2][4];
#pragma unroll
    for (int mi = 0; mi < 2; ++mi) {
        const bf16* qp = qkv + ((size_t)(b * TT) + t0 + w * 32 + mi * 16 + fr) * NQKV + h * HDq;
#pragma unroll
        for (int c = 0; c < 4; ++c) {
            short8 v = *reinterpret_cast<const short8*>(&qp[c * 32 + kq]);
#pragma unroll
            for (int e = 0; e < 8; ++e) {
                float f = __bfloat162float(__ushort_as_bfloat16((ushort)v[e])) * scl2;
                v[e] = (short)__bfloat16_as_ushort(__float2bfloat16(f));
            }
            qf[mi][c] = v;
        }
    }

    f32x4 acc[2][8];
#pragma unroll
    for (int mi = 0; mi < 2; ++mi)
#pragma unroll
        for (int n = 0; n < 8; ++n) acc[mi][n] = f32x4{0.f, 0.f, 0.f, 0.f};
    float lrow[2][4];
#pragma unroll
    for (int mi = 0; mi < 2; ++mi)
#pragma unroll
        for (int j = 0; j < 4; ++j) lrow[mi][j] = 0.f;

    int s_lo = t0 - window; if (s_lo < 0) s_lo = 0; s_lo &= ~63;
    const int s_end = t0 + 128;

    const bf16* Kg = qkv + (size_t)b * TT * NQKV + 2048 + kvh * HDq;
    const bf16* Vg = Kg + 512;

    const int str = tid >> 4;
    const int sti = tid & 15;
    const int vf  = tid & 15;
    const int vdc = (tid >> 4) * 8;

    short8 vr[4];

#pragma unroll
    for (int p = 0; p < 4; ++p) {
        int row = p * 16 + str;
        int c16 = sti ^ (row & 7);
        gll16(&Kg[(size_t)(s_lo + row) * NQKV + c16 * 8], (char*)Ks[0] + p * 4096 + tid * 16);
    }
#pragma unroll
    for (int i = 0; i < 4; ++i)
        vr[i] = *reinterpret_cast<const short8*>(&Vg[(size_t)(s_lo + 16 * i + vf) * NQKV + vdc]);
#pragma unroll
    for (int j = 0; j < 8; ++j) {
        short4v col;
        col[0] = vr[0][j]; col[1] = vr[1][j]; col[2] = vr[2][j]; col[3] = vr[3][j];
        *reinterpret_cast<short4v*>((char*)Vt[0] + (vdc + j) * 128 + ((8 * vf) ^ (j << 4))) = col;
    }
    __syncthreads();

    int cur = 0;
    for (int sk = s_lo; sk < s_end; sk += 64) {
        const bool hn = (sk + 64 < s_end);

        if (hn) {
#pragma unroll
            for (int p = 0; p < 4; ++p) {
                int row = p * 16 + str;
                int c16 = sti ^ (row & 7);
                gll16(&Kg[(size_t)(sk + 64 + row) * NQKV + c16 * 8],
                      (char*)Ks[cur ^ 1] + p * 4096 + tid * 16);
            }
#pragma unroll
            for (int i = 0; i < 4; ++i)
                vr[i] = *reinterpret_cast<const short8*>(&Vg[(size_t)(sk + 64 + 16 * i + vf) * NQKV + vdc]);
        }

        f32x4 S[2][4];
#pragma unroll
        for (int mi = 0; mi < 2; ++mi)
#pragma unroll
            for (int n = 0; n < 4; ++n) S[mi][n] = f32x4{0.f, 0.f, 0.f, 0.f};
        __builtin_amdgcn_s_setprio(1);
#pragma unroll
        for (int n = 0; n < 4; ++n) {
            int rb = n * 16 + fr;
#pragma unroll
            for (int c = 0; c < 4; ++c) {
                int colb = c * 64 + kq * 2;
                short8 kf = *reinterpret_cast<const short8*>(
                    (const char*)Ks[cur] + rb * 256 + (colb ^ ((rb & 7) << 4)));
                S[0][n] = MFMA16(qf[0][c], kf, S[0][n]);
                S[1][n] = MFMA16(qf[1][c], kf, S[1][n]);
            }
        }
        __builtin_amdgcn_s_setprio(0);

        const int rw0 = t0 + w * 32;
        const bool interior = (sk + 63 <= rw0) && (rw0 + 31 - sk <= window);
#pragma unroll
        for (int mi = 0; mi < 2; ++mi) {
#pragma unroll
            for (int j = 0; j < 4; ++j) {
                const int rl = hi * 4 + j;
                float s0, s1, s2, s3;
                if (interior) {
                    s0 = S[mi][0][j]; s1 = S[mi][1][j];
                    s2 = S[mi][2][j]; s3 = S[mi][3][j];
                } else {
                    const int r = rw0 + mi * 16 + rl;
                    int c0 = sk + fr, c1 = c0 + 16, c2 = c0 + 32, c3 = c0 + 48;
                    s0 = (c0 <= r && r - c0 <= window) ? S[mi][0][j] : -1e30f;
                    s1 = (c1 <= r && r - c1 <= window) ? S[mi][1][j] : -1e30f;
                    s2 = (c2 <= r && r - c2 <= window) ? S[mi][2][j] : -1e30f;
                    s3 = (c3 <= r && r - c3 <= window) ? S[mi][3][j] : -1e30f;
                }
                float p0 = exp2f(s0 - CAP);
                float p1 = exp2f(s1 - CAP);
                float p2 = exp2f(s2 - CAP);
                float p3 = exp2f(s3 - CAP);
                lrow[mi][j] += (p0 + p1) + (p2 + p3);
                short4v pk;
                pk[0] = (short)__bfloat16_as_ushort(__float2bfloat16(p0));
                pk[1] = (short)__bfloat16_as_ushort(__float2bfloat16(p1));
                pk[2] = (short)__bfloat16_as_ushort(__float2bfloat16(p2));
                pk[3] = (short)__bfloat16_as_ushort(__float2bfloat16(p3));
                const int prow = mi * 16 + rl;
                *reinterpret_cast<short4v*>(
                    (char*)Ps + w * 4096 + prow * 128 + ((8 * fr) ^ ((prow & 7) << 4))) = pk;
            }
        }

        if (hn) {
#pragma unroll
            for (int j = 0; j < 8; ++j) {
                short4v col;
                col[0] = vr[0][j]; col[1] = vr[1][j]; col[2] = vr[2][j]; col[3] = vr[3][j];
                *reinterpret_cast<short4v*>((char*)Vt[cur ^ 1] + (vdc + j) * 128 + ((8 * vf) ^ (j << 4))) = col;
            }
        }

        __builtin_amdgcn_s_setprio(1);
#pragma unroll
        for (int c2 = 0; c2 < 2; ++c2) {
            short8 pa0 = *reinterpret_cast<const short8*>(
                (char*)Ps + w * 4096 + fr * 128 + ((c2 * 64 + hi * 16) ^ ((fr & 7) << 4)));
            short8 pa1 = *reinterpret_cast<const short8*>(
                (char*)Ps + w * 4096 + (16 + fr) * 128 + ((c2 * 64 + hi * 16) ^ ((fr & 7) << 4)));
#pragma unroll
            for (int n = 0; n < 8; ++n) {
                short8 vb = *reinterpret_cast<const short8*>(
                    (char*)Vt[cur] + (n * 16 + fr) * 128 + ((c2 * 64 + hi * 16) ^ ((fr & 7) << 4)));
                acc[0][n] = MFMA16(pa0, vb, acc[0][n]);
                acc[1][n] = MFMA16(pa1, vb, acc[1][n]);
            }
        }
        __builtin_amdgcn_s_setprio(0);

        __syncthreads();
        cur ^= 1;
    }

#pragma unroll
    for (int mi = 0; mi < 2; ++mi)
#pragma unroll
        for (int j = 0; j < 4; ++j) {
            float l = lrow[mi][j];
#pragma unroll
            for (int mm = 1; mm < 16; mm <<= 1) l += __shfl_xor(l, mm);
            const int r = t0 + w * 32 + mi * 16 + hi * 4 + j;
            float inv = 1.f / l;
            bf16* yr = y + ((size_t)(b * TT) + r) * CC + h * HDq;
#pragma unroll
            for (int n = 0; n < 8; ++n)
                yr[n * 16 + fr] = __float2bfloat16(acc[mi][n][j] * inv);
        }
}

extern "C" void kernel_launch(void* const* d_in, const int* in_sizes, int n_in,
                              void* d_out, int out_size, void* d_ws, size_t ws_size,
                              hipStream_t stream) {
    const float* x     = (const float*)d_in[0];
    const float* ve    = (const float*)d_in[1];
    const float* cosb  = (const float*)d_in[2];
    const float* sinb  = (const float*)d_in[3];
    const float* Wq    = (const float*)d_in[4];
    const float* Wk    = (const float*)d_in[5];
    const float* Wv    = (const float*)d_in[6];
    const float* Wproj = (const float*)d_in[7];
    const float* Wgate = (const float*)d_in[8];
    const int*   winp  = (const int*)d_in[9];

    bf16* xb     = (bf16*)d_ws;
    bf16* wqkvb  = xb + (size_t)ROWS * CC;
    bf16* wprojb = wqkvb + (size_t)NQKV * CC;
    bf16* qkvb   = wprojb + (size_t)CC * CC;
    bf16* ybp1   = qkvb + (size_t)ROWS * NQKV;            // +16.8 MB
    float* lbuf  = (float*)(ybp1 + (size_t)ROWS * CC);    // +0.5 MB
    bf16* yb     = xb;   // O0 / final y alias (xb dead after qkv GEMM)

    const size_t needed = ((size_t)ROWS * CC + (size_t)NQKV * CC + (size_t)CC * CC +
                           (size_t)ROWS * NQKV + (size_t)ROWS * CC) * 2 +
                          (size_t)2 * ROWS * NHq * 4;
    const bool can_split = (ws_size >= needed);

    // 1) fused casts
    cast_all<<<18432, 256, 0, stream>>>(x, Wq, Wk, Wv, Wproj, xb);

    // 2) qkv = x @ [Wq;Wk;Wv]^T  (BK=64 swizzled)
    gemm_bt<0><<<dim3(ROWS / 128, NQKV / 128), 256, 0, stream>>>(xb, wqkvb, qkvb, ROWS, NQKV, CC);

    // 3) gate/ve add + RoPE + RMSNorm (vectorized, in place)
    postproc<<<ROWS, 256, 0, stream>>>(x, ve, cosb, sinb, Wgate, qkvb);

    // 4) attention
    if (can_split) {
        attn_split<<<2 * BB * NHq * (TT / 128), 256, 0, stream>>>(qkvb, yb, ybp1, lbuf, winp);
        attn_combine<<<ROWS, 256, 0, stream>>>(yb, ybp1, lbuf);
    } else {
        attn_mfma<<<BB * NHq * (TT / 128), 256, 0, stream>>>(qkvb, yb, winp);
    }

    // 5) out = y @ Wproj^T (fp32 out)
    gemm_bt<1><<<dim3(ROWS / 128, CC / 128), 256, 0, stream>>>(yb, wprojb, d_out, ROWS, CC, CC);
}

// Round 23
// 175.686 us; speedup vs baseline: 1.3298x; 1.3298x over previous
//
#include <hip/hip_runtime.h>
#include <hip/hip_bf16.h>

// Problem constants (reference: B=2, T=2048, C=2048, NH=16, NKV=4, HD=128, GATE_CH=12)
#define BB   2
#define TT   2048
#define CC   2048
#define NHq  16
#define NKVq 4
#define HDq  128
#define ROWS (BB*TT)          // 4096
#define NQKV (NHq*HDq + 2*NKVq*HDq)  // 3072

using bf16 = __hip_bfloat16;
using short8  = __attribute__((ext_vector_type(8))) short;
using short4v = __attribute__((ext_vector_type(4))) short;
using f32x4   = __attribute__((ext_vector_type(4))) float;

#define MFMA16(a,b,c) __builtin_amdgcn_mfma_f32_16x16x32_bf16((a),(b),(c),0,0,0)

// async global->LDS, 16B per lane. LDS dest must be wave-uniform-base + lane*16.
__device__ __forceinline__ void gll16(const bf16* g, void* l) {
    __builtin_amdgcn_global_load_lds((const __attribute__((address_space(1))) void*)g,
                                     (__attribute__((address_space(3))) void*)l,
                                     16, 0, 0);
}

// ---------------- fused cast: all fp32 inputs -> contiguous bf16 ws regions ----------------
// dst layout: [xb 8388608 | wq 4194304 | wk 1048576 | wv 1048576 | wproj 4194304]
__global__ void cast_all(const float* __restrict__ x,  const float* __restrict__ wq,
                         const float* __restrict__ wk, const float* __restrict__ wv,
                         const float* __restrict__ wp, bf16* __restrict__ dst) {
    long e = ((long)blockIdx.x * 256 + threadIdx.x) * 4;
    const float* src; long off;
    if (e < 8388608L)       { src = x;  off = e; }
    else if (e < 12582912L) { src = wq; off = e - 8388608L; }
    else if (e < 13631488L) { src = wk; off = e - 12582912L; }
    else if (e < 14680064L) { src = wv; off = e - 13631488L; }
    else                    { src = wp; off = e - 14680064L; }
    float4 v = *reinterpret_cast<const float4*>(src + off);
    ushort4 o;
    o.x = __bfloat16_as_ushort(__float2bfloat16(v.x));
    o.y = __bfloat16_as_ushort(__float2bfloat16(v.y));
    o.z = __bfloat16_as_ushort(__float2bfloat16(v.z));
    o.w = __bfloat16_as_ushort(__float2bfloat16(v.w));
    *reinterpret_cast<ushort4*>(dst + e) = o;
}

// ---------------- bf16 MFMA GEMM: 128x128 tile, BK=64, XOR-swizzled LDS (R12 best) ----------------
template<int OUT_F32>
__global__ __launch_bounds__(256) void gemm_bt(const bf16* __restrict__ A,
                                               const bf16* __restrict__ B,
                                               void* __restrict__ Cp,
                                               int M, int N, int K) {
    const int bm = blockIdx.x * 128;
    const int bn = blockIdx.y * 128;
    const int tid = threadIdx.x;
    const int lane = tid & 63;
    const int w = tid >> 6;
    const int wr = w >> 1, wc = w & 1;   // 2x2 waves of 64x64

    __shared__ __align__(16) bf16 As[128 * 64];   // 16 KB, swizzled storage
    __shared__ __align__(16) bf16 Bs[128 * 64];   // 16 KB

    f32x4 acc[4][4];
#pragma unroll
    for (int i = 0; i < 4; ++i)
#pragma unroll
        for (int j = 0; j < 4; ++j) acc[i][j] = f32x4{0.f, 0.f, 0.f, 0.f};

    const int srow = tid >> 3;          // 0..31 (+ i*32)
    const int sch  = tid & 7;           // dest 16B chunk

    const int fr = lane & 15;
    const int kq = lane >> 4;           // 0..3

    for (int k0 = 0; k0 < K; k0 += 64) {
        __syncthreads();
#pragma unroll
        for (int i = 0; i < 4; ++i) {
            int row = i * 32 + srow;
            int c = sch ^ (row & 7);    // pre-swizzled source chunk
            gll16(&A[(size_t)(bm + row) * K + k0 + c * 8], (char*)As + i * 4096 + tid * 16);
            gll16(&B[(size_t)(bn + row) * K + k0 + c * 8], (char*)Bs + i * 4096 + tid * 16);
        }
        __syncthreads();

#pragma unroll
        for (int kk = 0; kk < 2; ++kk) {
            short8 af[4], bfr[4];
#pragma unroll
            for (int m = 0; m < 4; ++m) {
                int r = wr * 64 + m * 16 + fr;
                af[m] = *reinterpret_cast<const short8*>(
                    (const char*)As + r * 128 + (((kk * 4 + kq) ^ (r & 7)) * 16));
            }
#pragma unroll
            for (int n = 0; n < 4; ++n) {
                int r = wc * 64 + n * 16 + fr;
                bfr[n] = *reinterpret_cast<const short8*>(
                    (const char*)Bs + r * 128 + (((kk * 4 + kq) ^ (r & 7)) * 16));
            }
            __builtin_amdgcn_s_setprio(1);
#pragma unroll
            for (int m = 0; m < 4; ++m)
#pragma unroll
                for (int n = 0; n < 4; ++n)
                    acc[m][n] = MFMA16(af[m], bfr[n], acc[m][n]);
            __builtin_amdgcn_s_setprio(0);
        }
    }

    const int cr = (lane >> 4) * 4;
    const int cc = lane & 15;
#pragma unroll
    for (int m = 0; m < 4; ++m)
#pragma unroll
        for (int n = 0; n < 4; ++n) {
            int row = bm + wr * 64 + m * 16 + cr;
            int col = bn + wc * 64 + n * 16 + cc;
#pragma unroll
            for (int j = 0; j < 4; ++j) {
                float v = acc[m][n][j];
                if (OUT_F32) ((float*)Cp)[(size_t)(row + j) * N + col] = v;
                else         ((bf16*)Cp)[(size_t)(row + j) * N + col] = __float2bfloat16(v);
            }
        }
}

// ---------------- postproc v2 (vectorized) ----------------
__global__ __launch_bounds__(256) void postproc(const float* __restrict__ x,
                                                const float* __restrict__ ve,
                                                const float* __restrict__ cosb,
                                                const float* __restrict__ sinb,
                                                const float* __restrict__ Wgate,
                                                bf16* __restrict__ qkv) {
    const int row = blockIdx.x;            // b*T + t
    const int t = row & (TT - 1);
    const int tid = threadIdx.x;
    __shared__ float gate_s[NKVq];
    if (tid < NKVq) {
        float g = 0.f;
#pragma unroll
        for (int c = 0; c < 12; ++c) g += x[(size_t)row * CC + c] * Wgate[tid * 12 + c];
        gate_s[tid] = 3.0f / (1.0f + __expf(-g));
    }
    __syncthreads();

    bf16* qkvr = qkv + (size_t)row * NQKV;

    if (tid < 160) {
        const int hh = tid >> 3, c = tid & 7;
        const int off = (hh < NHq) ? hh * HDq : 2048 + (hh - NHq) * HDq;
        const int d0 = c * 8;
        short8 x1v = *reinterpret_cast<const short8*>(&qkvr[off + d0]);
        short8 x2v = *reinterpret_cast<const short8*>(&qkvr[off + 64 + d0]);
        float4 c0 = *reinterpret_cast<const float4*>(&cosb[(size_t)t * 64 + d0]);
        float4 c1 = *reinterpret_cast<const float4*>(&cosb[(size_t)t * 64 + d0 + 4]);
        float4 s0 = *reinterpret_cast<const float4*>(&sinb[(size_t)t * 64 + d0]);
        float4 s1 = *reinterpret_cast<const float4*>(&sinb[(size_t)t * 64 + d0 + 4]);
        float cv[8] = {c0.x, c0.y, c0.z, c0.w, c1.x, c1.y, c1.z, c1.w};
        float sv[8] = {s0.x, s0.y, s0.z, s0.w, s1.x, s1.y, s1.z, s1.w};
        float r1[8], r2[8], ss = 0.f;
#pragma unroll
        for (int e = 0; e < 8; ++e) {
            float x1 = __bfloat162float(__ushort_as_bfloat16((ushort)x1v[e]));
            float x2 = __bfloat162float(__ushort_as_bfloat16((ushort)x2v[e]));
            r1[e] =  x1 * cv[e] + x2 * sv[e];
            r2[e] = -x1 * sv[e] + x2 * cv[e];
            ss += r1[e] * r1[e] + r2[e] * r2[e];
        }
#pragma unroll
        for (int m = 1; m < 8; m <<= 1) ss += __shfl_xor(ss, m);
        float sc = rsqrtf(ss * (1.0f / 128.0f) + 1e-6f) * 1.2f;
        short8 o1, o2;
#pragma unroll
        for (int e = 0; e < 8; ++e) {
            o1[e] = (short)__bfloat16_as_ushort(__float2bfloat16(r1[e] * sc));
            o2[e] = (short)__bfloat16_as_ushort(__float2bfloat16(r2[e] * sc));
        }
        *reinterpret_cast<short8*>(&qkvr[off + d0])      = o1;
        *reinterpret_cast<short8*>(&qkvr[off + 64 + d0]) = o2;
    } else if (tid < 224) {
        const int u = tid - 160;
        const int e0 = u * 8;
        short8 vv = *reinterpret_cast<const short8*>(&qkvr[2560 + e0]);
        float4 v0 = *reinterpret_cast<const float4*>(&ve[(size_t)row * 512 + e0]);
        float4 v1 = *reinterpret_cast<const float4*>(&ve[(size_t)row * 512 + e0 + 4]);
        float vef[8] = {v0.x, v0.y, v0.z, v0.w, v1.x, v1.y, v1.z, v1.w};
        const float g = gate_s[u >> 4];
        short8 o;
#pragma unroll
        for (int e = 0; e < 8; ++e) {
            float v = __bfloat162float(__ushort_as_bfloat16((ushort)vv[e])) + g * vef[e];
            o[e] = (short)__bfloat16_as_ushort(__float2bfloat16(v));
        }
        *reinterpret_cast<short8*>(&qkvr[2560 + e0]) = o;
    }
}

// ---------------- MFMA flash attention v9 (best: 62 us) ----------------
// Full dbuf (K+V), ONE barrier/tile, prescaled Q, fixed-cap softmax, 80 KB LDS.
__global__ __launch_bounds__(256, 2) void attn_mfma(const bf16* __restrict__ qkv,
                                                    bf16* __restrict__ y,
                                                    const int* __restrict__ winp) {
    const int bid = blockIdx.x;
    const int group = bid >> 8, idx = bid & 255;
    const int bh = idx >> 3, jj = idx & 7;
    const int qt = group ? jj : (15 - jj);
    const int h = bh & 15, b = bh >> 4;
    const int t0 = qt * 128;
    const int kvh = h >> 2;
    const int tid = threadIdx.x;
    const int lane = tid & 63;
    const int w = tid >> 6;
    const int window = winp[0];

    __shared__ __align__(16) bf16 Ks[2][64 * 128];  // 32 KB
    __shared__ __align__(16) bf16 Vt[2][128 * 64];  // 32 KB
    __shared__ __align__(16) bf16 Ps[4][32 * 64];   // 16 KB

    const int fr = lane & 15;
    const int kq = (lane >> 4) * 8;
    const int hi = lane >> 4;
    const float scl2 = 0.08838834764831845f * 1.4426950408889634f;  // 1/sqrt(128)*log2(e)
    const float CAP = 24.0f;   // |s| <= 1.44*sqrt(128)*log2e ~= 23.5 after RMSNorm

    // Q fragments, PRE-SCALED by scl2
    short8 qf[2][4];
#pragma unroll
    for (int mi = 0; mi < 2; ++mi) {
        const bf16* qp = qkv + ((size_t)(b * TT) + t0 + w * 32 + mi * 16 + fr) * NQKV + h * HDq;
#pragma unroll
        for (int c = 0; c < 4; ++c) {
            short8 v = *reinterpret_cast<const short8*>(&qp[c * 32 + kq]);
#pragma unroll
            for (int e = 0; e < 8; ++e) {
                float f = __bfloat162float(__ushort_as_bfloat16((ushort)v[e])) * scl2;
                v[e] = (short)__bfloat16_as_ushort(__float2bfloat16(f));
            }
            qf[mi][c] = v;
        }
    }

    f32x4 acc[2][8];
#pragma unroll
    for (int mi = 0; mi < 2; ++mi)
#pragma unroll
        for (int n = 0; n < 8; ++n) acc[mi][n] = f32x4{0.f, 0.f, 0.f, 0.f};
    float lrow[2][4];
#pragma unroll
    for (int mi = 0; mi < 2; ++mi)
#pragma unroll
        for (int j = 0; j < 4; ++j) lrow[mi][j] = 0.f;

    int s_lo = t0 - window; if (s_lo < 0) s_lo = 0; s_lo &= ~63;
    const int s_end = t0 + 128;

    const bf16* Kg = qkv + (size_t)b * TT * NQKV + 2048 + kvh * HDq;
    const bf16* Vg = Kg + 512;

    const int str = tid >> 4;
    const int sti = tid & 15;
    const int vf  = tid & 15;
    const int vdc = (tid >> 4) * 8;

    short8 vr[4];

    // ---- prime: stage tile s_lo into buf 0 ----
#pragma unroll
    for (int p = 0; p < 4; ++p) {
        int row = p * 16 + str;
        int c16 = sti ^ (row & 7);
        gll16(&Kg[(size_t)(s_lo + row) * NQKV + c16 * 8], (char*)Ks[0] + p * 4096 + tid * 16);
    }
#pragma unroll
    for (int i = 0; i < 4; ++i)
        vr[i] = *reinterpret_cast<const short8*>(&Vg[(size_t)(s_lo + 16 * i + vf) * NQKV + vdc]);
#pragma unroll
    for (int j = 0; j < 8; ++j) {
        short4v col;
        col[0] = vr[0][j]; col[1] = vr[1][j]; col[2] = vr[2][j]; col[3] = vr[3][j];
        *reinterpret_cast<short4v*>((char*)Vt[0] + (vdc + j) * 128 + ((8 * vf) ^ (j << 4))) = col;
    }
    __syncthreads();   // buf0 (K + V) ready

    int cur = 0;
    for (int sk = s_lo; sk < s_end; sk += 64) {
        const bool hn = (sk + 64 < s_end);

        // ---- issue next tile's loads: K -> Ks[cur^1] (async), V -> regs ----
        if (hn) {
#pragma unroll
            for (int p = 0; p < 4; ++p) {
                int row = p * 16 + str;
                int c16 = sti ^ (row & 7);
                gll16(&Kg[(size_t)(sk + 64 + row) * NQKV + c16 * 8],
                      (char*)Ks[cur ^ 1] + p * 4096 + tid * 16);
            }
#pragma unroll
            for (int i = 0; i < 4; ++i)
                vr[i] = *reinterpret_cast<const short8*>(&Vg[(size_t)(sk + 64 + 16 * i + vf) * NQKV + vdc]);
        }

        // ---- QK^T on Ks[cur] (Q pre-scaled) ----
        f32x4 S[2][4];
#pragma unroll
        for (int mi = 0; mi < 2; ++mi)
#pragma unroll
            for (int n = 0; n < 4; ++n) S[mi][n] = f32x4{0.f, 0.f, 0.f, 0.f};
        __builtin_amdgcn_s_setprio(1);
#pragma unroll
        for (int n = 0; n < 4; ++n) {
            int rb = n * 16 + fr;
#pragma unroll
            for (int c = 0; c < 4; ++c) {
                int colb = c * 64 + kq * 2;
                short8 kf = *reinterpret_cast<const short8*>(
                    (const char*)Ks[cur] + rb * 256 + (colb ^ ((rb & 7) << 4)));
                S[0][n] = MFMA16(qf[0][c], kf, S[0][n]);
                S[1][n] = MFMA16(qf[1][c], kf, S[1][n]);
            }
        }
        __builtin_amdgcn_s_setprio(0);

        // ---- fixed-cap softmax -> Ps ----
        const int rw0 = t0 + w * 32;
        const bool interior = (sk + 63 <= rw0) && (rw0 + 31 - sk <= window);
#pragma unroll
        for (int mi = 0; mi < 2; ++mi) {
#pragma unroll
            for (int j = 0; j < 4; ++j) {
                const int rl = hi * 4 + j;
                float s0, s1, s2, s3;
                if (interior) {
                    s0 = S[mi][0][j]; s1 = S[mi][1][j];
                    s2 = S[mi][2][j]; s3 = S[mi][3][j];
                } else {
                    const int r = rw0 + mi * 16 + rl;
                    int c0 = sk + fr, c1 = c0 + 16, c2 = c0 + 32, c3 = c0 + 48;
                    s0 = (c0 <= r && r - c0 <= window) ? S[mi][0][j] : -1e30f;
                    s1 = (c1 <= r && r - c1 <= window) ? S[mi][1][j] : -1e30f;
                    s2 = (c2 <= r && r - c2 <= window) ? S[mi][2][j] : -1e30f;
                    s3 = (c3 <= r && r - c3 <= window) ? S[mi][3][j] : -1e30f;
                }
                float p0 = exp2f(s0 - CAP);
                float p1 = exp2f(s1 - CAP);
                float p2 = exp2f(s2 - CAP);
                float p3 = exp2f(s3 - CAP);
                lrow[mi][j] += (p0 + p1) + (p2 + p3);
                short4v pk;
                pk[0] = (short)__bfloat16_as_ushort(__float2bfloat16(p0));
                pk[1] = (short)__bfloat16_as_ushort(__float2bfloat16(p1));
                pk[2] = (short)__bfloat16_as_ushort(__float2bfloat16(p2));
                pk[3] = (short)__bfloat16_as_ushort(__float2bfloat16(p3));
                const int prow = mi * 16 + rl;
                *reinterpret_cast<short4v*>(
                    (char*)Ps + w * 4096 + prow * 128 + ((8 * fr) ^ ((prow & 7) << 4))) = pk;
            }
        }

        // ---- write next V into Vt[cur^1] (vr arrived; nobody reads cur^1 this iter) ----
        if (hn) {
#pragma unroll
            for (int j = 0; j < 8; ++j) {
                short4v col;
                col[0] = vr[0][j]; col[1] = vr[1][j]; col[2] = vr[2][j]; col[3] = vr[3][j];
                *reinterpret_cast<short4v*>((char*)Vt[cur ^ 1] + (vdc + j) * 128 + ((8 * vf) ^ (j << 4))) = col;
            }
        }

        // ---- PV on Ps + Vt[cur] ----
        __builtin_amdgcn_s_setprio(1);
#pragma unroll
        for (int c2 = 0; c2 < 2; ++c2) {
            short8 pa0 = *reinterpret_cast<const short8*>(
                (char*)Ps + w * 4096 + fr * 128 + ((c2 * 64 + hi * 16) ^ ((fr & 7) << 4)));
            short8 pa1 = *reinterpret_cast<const short8*>(
                (char*)Ps + w * 4096 + (16 + fr) * 128 + ((c2 * 64 + hi * 16) ^ ((fr & 7) << 4)));
#pragma unroll
            for (int n = 0; n < 8; ++n) {
                short8 vb = *reinterpret_cast<const short8*>(
                    (char*)Vt[cur] + (n * 16 + fr) * 128 + ((c2 * 64 + hi * 16) ^ ((fr & 7) << 4)));
                acc[0][n] = MFMA16(pa0, vb, acc[0][n]);
                acc[1][n] = MFMA16(pa1, vb, acc[1][n]);
            }
        }
        __builtin_amdgcn_s_setprio(0);

        __syncthreads();   // ONE barrier/tile: drains K gll16 + Vt writes; publishes buf cur^1
        cur ^= 1;
    }

    // ---- epilogue: reduce deferred l-sum, normalize + write ----
#pragma unroll
    for (int mi = 0; mi < 2; ++mi)
#pragma unroll
        for (int j = 0; j < 4; ++j) {
            float l = lrow[mi][j];
#pragma unroll
            for (int mm = 1; mm < 16; mm <<= 1) l += __shfl_xor(l, mm);
            const int r = t0 + w * 32 + mi * 16 + hi * 4 + j;
            float inv = 1.f / l;
            bf16* yr = y + ((size_t)(b * TT) + r) * CC + h * HDq;
#pragma unroll
            for (int n = 0; n < 8; ++n)
                yr[n * 16 + fr] = __float2bfloat16(acc[mi][n][j] * inv);
        }
}

extern "C" void kernel_launch(void* const* d_in, const int* in_sizes, int n_in,
                              void* d_out, int out_size, void* d_ws, size_t ws_size,
                              hipStream_t stream) {
    const float* x     = (const float*)d_in[0];
    const float* ve    = (const float*)d_in[1];
    const float* cosb  = (const float*)d_in[2];
    const float* sinb  = (const float*)d_in[3];
    const float* Wq    = (const float*)d_in[4];
    const float* Wk    = (const float*)d_in[5];
    const float* Wv    = (const float*)d_in[6];
    const float* Wproj = (const float*)d_in[7];
    const float* Wgate = (const float*)d_in[8];
    const int*   winp  = (const int*)d_in[9];

    bf16* xb     = (bf16*)d_ws;
    bf16* wqkvb  = xb + (size_t)ROWS * CC;
    bf16* wprojb = wqkvb + (size_t)NQKV * CC;
    bf16* qkvb   = wprojb + (size_t)CC * CC;
    bf16* yb     = xb;   // alias: xb dead after qkv GEMM

    // 1) fused casts
    cast_all<<<18432, 256, 0, stream>>>(x, Wq, Wk, Wv, Wproj, xb);

    // 2) qkv = x @ [Wq;Wk;Wv]^T  (BK=64 swizzled)
    gemm_bt<0><<<dim3(ROWS / 128, NQKV / 128), 256, 0, stream>>>(xb, wqkvb, qkvb, ROWS, NQKV, CC);

    // 3) gate/ve add + RoPE + RMSNorm (vectorized, in place)
    postproc<<<ROWS, 256, 0, stream>>>(x, ve, cosb, sinb, Wgate, qkvb);

    // 4) MFMA flash attention -> yb  (v9: full dbuf, 1 barrier/tile — 62 us best)
    attn_mfma<<<BB * NHq * (TT / 128), 256, 0, stream>>>(qkvb, yb, winp);

    // 5) out = y @ Wproj^T (fp32 out)
    gemm_bt<1><<<dim3(ROWS / 128, CC / 128), 256, 0, stream>>>(yb, wprojb, d_out, ROWS, CC, CC);
}